// Round 7
// baseline (767.924 us; speedup 1.0000x reference)
//
#include <hip/hip_runtime.h>
#include <hip/hip_fp16.h>

// Log-sparse attention, B=4 H=8 L=4096 E=64 fp32, win_len<=32.
// Lane-per-query. Round-7: eliminate the fp32 score array (the long-lived
// state that kept spilling). Scores stored as PACKED fp16 (20 regs); softmax
// folded to C = m + log(den); PV recomputes p = exp(s-C) on the fly.
// Q loaded once, full row, packed bf16 (32 regs). No launch_bounds cap --
// live sets ~90-110, allocator should land ~150-180 VGPR with zero spill.

constexpr int L       = 4096;
constexpr int E       = 64;
constexpr int QB      = 256;
constexpr int WMAX    = 32;
constexpr int WROWS   = QB + WMAX;   // 288
constexpr int RSTRIDE = 144;         // 128 B bf16 row + 16 pad
constexpr int TPB_SEQ = L / QB;      // 16
constexpr int NP2     = 6;           // dists 64..2048
constexpr int NW      = WMAX + 1;    // 33 window keys
constexpr int NK      = NW + NP2;    // 39 candidates

__device__ __forceinline__ unsigned pack2_bf16(float a, float b) {
    unsigned ua = __float_as_uint(a);
    unsigned ub = __float_as_uint(b);
    unsigned ra = (ua + 0x7FFFu + ((ua >> 16) & 1u)) >> 16;  // RNE
    unsigned rb = (ub + 0x7FFFu + ((ub >> 16) & 1u)) >> 16;
    return ra | (rb << 16);
}
__device__ __forceinline__ float bf_lo(unsigned w) { return __uint_as_float(w << 16); }
__device__ __forceinline__ float bf_hi(unsigned w) { return __uint_as_float(w & 0xFFFF0000u); }

// fp16 score pack/unpack (hi selector is compile-time after unroll)
__device__ __forceinline__ unsigned f16bits(float s) {
    return (unsigned)__half_as_ushort(__float2half(s));
}
__device__ __forceinline__ float up16(unsigned w, int hi) {
    unsigned short u = hi ? (unsigned short)(w >> 16) : (unsigned short)(w & 0xFFFFu);
    return __half2float(__ushort_as_half(u));
}

__global__ void logsparse_attn(
    const float* __restrict__ q,
    const float* __restrict__ k,
    const float* __restrict__ v,
    float* __restrict__ out,
    const int* __restrict__ win_ptr)
{
    __shared__ alignas(16) unsigned char buf[WROWS * RSTRIDE];  // 41472 B

    const int bid = blockIdx.x, nb = gridDim.x;
    int swz = bid;
    if ((nb & 7) == 0) {                        // bijective XCD swizzle
        const int cpx = nb >> 3;
        swz = (bid & 7) * cpx + (bid >> 3);
    }
    const int bh  = swz / TPB_SEQ;
    const int t   = (swz % TPB_SEQ) * QB;
    const int tid = threadIdx.x;
    const int i   = t + tid;
    int win = *win_ptr; win = min(win, WMAX);

    const size_t base = (size_t)bh * (L * E);
    const float* kb = k + base;
    const float* vb = v + base;

    // ---- stage K window rows [t-WMAX, t+QB) as bf16 (coalesced) ----
    #pragma unroll 4
    for (int it = 0; it < (WROWS * (E / 4)) / QB; ++it) {   // 18 iters
        int idx = tid + it * QB;
        int row = idx >> 4, e4 = idx & 15;
        int j = t - WMAX + row; j = max(j, 0);
        const float4 f = *(const float4*)(kb + (size_t)j * E + e4 * 4);
        uint2 pk; pk.x = pack2_bf16(f.x, f.y); pk.y = pack2_bf16(f.z, f.w);
        *(uint2*)(buf + row * RSTRIDE + e4 * 8) = pk;
    }
    __syncthreads();

    // ---- full q row, scaled (1/8), packed bf16 -> 32 regs ----
    unsigned qp[32];
    {
        const float* qptr = q + base + (size_t)i * E;
        #pragma unroll
        for (int e4 = 0; e4 < 16; ++e4) {
            float4 f = *(const float4*)(qptr + e4 * 4);
            qp[e4*2+0] = pack2_bf16(f.x * 0.125f, f.y * 0.125f);
            qp[e4*2+1] = pack2_bf16(f.z * 0.125f, f.w * 0.125f);
        }
    }
    __builtin_amdgcn_sched_barrier(0);

    // ---- scores -> packed fp16 sp[20] ----
    unsigned sp[(NK + 1) / 2];

    // window offsets 0..32 (LDS, bf16, full row = 8 x b128)
    #pragma unroll
    for (int o = 0; o < NW; ++o) {
        const int4* rp = (const int4*)(buf + (tid + (WMAX - o)) * RSTRIDE);
        float a0 = 0.f, a1 = 0.f, a2 = 0.f, a3 = 0.f;
        #pragma unroll
        for (int e8 = 0; e8 < 8; ++e8) {
            int4 w = rp[e8];
            unsigned q0 = qp[e8*4+0], q1 = qp[e8*4+1], q2 = qp[e8*4+2], q3 = qp[e8*4+3];
            a0 = fmaf(bf_lo(w.x), bf_lo(q0), a0); a1 = fmaf(bf_hi(w.x), bf_hi(q0), a1);
            a2 = fmaf(bf_lo(w.y), bf_lo(q1), a2); a3 = fmaf(bf_hi(w.y), bf_hi(q1), a3);
            a0 = fmaf(bf_lo(w.z), bf_lo(q2), a0); a1 = fmaf(bf_hi(w.z), bf_hi(q2), a1);
            a2 = fmaf(bf_lo(w.w), bf_lo(q3), a2); a3 = fmaf(bf_hi(w.w), bf_hi(q3), a3);
        }
        float s = (a0 + a1) + (a2 + a3);
        const bool isp2  = (o > 0) && ((o & (o - 1)) == 0);
        const bool valid = ((o <= win) || isp2) && (o <= i);
        if (!valid) s = -60000.f;
        unsigned hb = f16bits(s);
        if ((o & 1) == 0) sp[o >> 1] = hb; else sp[o >> 1] |= hb << 16;
        if ((o & 3) == 3) __builtin_amdgcn_sched_barrier(0);
    }

    // pow2 dists 64..2048 (global fp32, row in two 8-float4 halves)
    #pragma unroll
    for (int dd = 0; dd < NP2; ++dd) {
        const int d = 64 << dd;
        const int o = NW + dd;
        float s = -60000.f;
        if ((i | 63) >= d) {                    // wave-uniform skip
            const int j = max(i - d, 0);
            const float* kr = kb + (size_t)j * E;
            float a0 = 0.f, a1 = 0.f, a2 = 0.f, a3 = 0.f;
            #pragma unroll
            for (int e4 = 0; e4 < 8; ++e4) {
                float4 f = *(const float4*)(kr + e4 * 4);
                unsigned w0 = qp[e4*2+0], w1 = qp[e4*2+1];
                a0 = fmaf(f.x, bf_lo(w0), a0); a1 = fmaf(f.y, bf_hi(w0), a1);
                a2 = fmaf(f.z, bf_lo(w1), a2); a3 = fmaf(f.w, bf_hi(w1), a3);
            }
            __builtin_amdgcn_sched_barrier(0);
            #pragma unroll
            for (int e4 = 8; e4 < 16; ++e4) {
                float4 f = *(const float4*)(kr + e4 * 4);
                unsigned w0 = qp[e4*2+0], w1 = qp[e4*2+1];
                a0 = fmaf(f.x, bf_lo(w0), a0); a1 = fmaf(f.y, bf_hi(w0), a1);
                a2 = fmaf(f.z, bf_lo(w1), a2); a3 = fmaf(f.w, bf_hi(w1), a3);
            }
            if (i >= d) s = (a0 + a1) + (a2 + a3);
        }
        unsigned hb = f16bits(s);
        if ((o & 1) == 0) sp[o >> 1] = hb; else sp[o >> 1] |= hb << 16;
        __builtin_amdgcn_sched_barrier(0);
    }

    // ---- softmax folded into one constant: C = m + log(den) ----
    float m = -1e30f;
    #pragma unroll
    for (int a = 0; a < NK; ++a) m = fmaxf(m, up16(sp[a >> 1], a & 1));
    float den = 0.f;
    #pragma unroll
    for (int a = 0; a < NK; ++a) den += __expf(up16(sp[a >> 1], a & 1) - m);
    const float C = m + __logf(den);

    __syncthreads();   // done reading K from buf

    // ---- restage V window rows as bf16 ----
    #pragma unroll 4
    for (int it = 0; it < (WROWS * (E / 4)) / QB; ++it) {
        int idx = tid + it * QB;
        int row = idx >> 4, e4 = idx & 15;
        int j = t - WMAX + row; j = max(j, 0);
        const float4 f = *(const float4*)(vb + (size_t)j * E + e4 * 4);
        uint2 pk; pk.x = pack2_bf16(f.x, f.y); pk.y = pack2_bf16(f.z, f.w);
        *(uint2*)(buf + row * RSTRIDE + e4 * 8) = pk;
    }
    __syncthreads();

    // ---- PV: single pass, acc[64]; p recomputed from packed s ----
    float acc[E];
    #pragma unroll
    for (int e = 0; e < E; ++e) acc[e] = 0.f;

    #pragma unroll
    for (int o = 0; o < NW; ++o) {
        const float pd = __expf(up16(sp[o >> 1], o & 1) - C);   // 0 if masked
        const int4* rp = (const int4*)(buf + (tid + (WMAX - o)) * RSTRIDE);
        #pragma unroll
        for (int e8 = 0; e8 < 8; ++e8) {
            int4 w = rp[e8]; int eb = e8 * 8;
            acc[eb+0] = fmaf(bf_lo(w.x), pd, acc[eb+0]);
            acc[eb+1] = fmaf(bf_hi(w.x), pd, acc[eb+1]);
            acc[eb+2] = fmaf(bf_lo(w.y), pd, acc[eb+2]);
            acc[eb+3] = fmaf(bf_hi(w.y), pd, acc[eb+3]);
            acc[eb+4] = fmaf(bf_lo(w.z), pd, acc[eb+4]);
            acc[eb+5] = fmaf(bf_hi(w.z), pd, acc[eb+5]);
            acc[eb+6] = fmaf(bf_lo(w.w), pd, acc[eb+6]);
            acc[eb+7] = fmaf(bf_hi(w.w), pd, acc[eb+7]);
        }
        if ((o & 3) == 3) __builtin_amdgcn_sched_barrier(0);
    }

    #pragma unroll
    for (int dd = 0; dd < NP2; ++dd) {
        const int d = 64 << dd;
        const int o = NW + dd;
        if ((i | 63) >= d) {
            const int j = max(i - d, 0);
            const float* vr = vb + (size_t)j * E;
            const float pd = __expf(up16(sp[o >> 1], o & 1) - C);  // 0 if masked
            #pragma unroll
            for (int e4 = 0; e4 < 8; ++e4) {
                float4 f = *(const float4*)(vr + e4 * 4);
                acc[e4*4+0] = fmaf(f.x, pd, acc[e4*4+0]);
                acc[e4*4+1] = fmaf(f.y, pd, acc[e4*4+1]);
                acc[e4*4+2] = fmaf(f.z, pd, acc[e4*4+2]);
                acc[e4*4+3] = fmaf(f.w, pd, acc[e4*4+3]);
            }
            __builtin_amdgcn_sched_barrier(0);
            #pragma unroll
            for (int e4 = 8; e4 < 16; ++e4) {
                float4 f = *(const float4*)(vr + e4 * 4);
                acc[e4*4+0] = fmaf(f.x, pd, acc[e4*4+0]);
                acc[e4*4+1] = fmaf(f.y, pd, acc[e4*4+1]);
                acc[e4*4+2] = fmaf(f.z, pd, acc[e4*4+2]);
                acc[e4*4+3] = fmaf(f.w, pd, acc[e4*4+3]);
            }
        }
        __builtin_amdgcn_sched_barrier(0);
    }

    // ---- write out ----
    float* op = out + base + (size_t)i * E;
    #pragma unroll
    for (int e4 = 0; e4 < 16; ++e4) {
        float4 o4;
        o4.x = acc[e4*4+0]; o4.y = acc[e4*4+1];
        o4.z = acc[e4*4+2]; o4.w = acc[e4*4+3];
        *(float4*)(op + e4 * 4) = o4;
    }
}

extern "C" void kernel_launch(void* const* d_in, const int* in_sizes, int n_in,
                              void* d_out, int out_size, void* d_ws, size_t ws_size,
                              hipStream_t stream) {
    const float* q = (const float*)d_in[0];
    const float* k = (const float*)d_in[1];
    const float* v = (const float*)d_in[2];
    const int* win = (const int*)d_in[3];
    float* out = (float*)d_out;

    const int n_rows = in_sizes[0] / E;       // B*H*L = 131072
    const int blocks = n_rows / QB;           // 512
    logsparse_attn<<<blocks, QB, 0, stream>>>(q, k, v, out, win);
}

// Round 8
// 615.140 us; speedup vs baseline: 1.2484x; 1.2484x over previous
//
#include <hip/hip_runtime.h>
#include <hip/hip_fp16.h>

// Log-sparse attention, B=4 H=8 L=4096 E=64 fp32, win_len<=32.
// Lane-per-query. Round-8: R7 structure (fp16-packed scores, C-folded
// softmax, single-pass PV) + allocator PINNED at 3 waves/EU:
//   - LDS 41.5KB already limits us to 3 blocks/CU; amdgpu_waves_per_eu(3,3)
//     makes the register allocator budget exactly that (~170 VGPR), instead
//     of R7's heuristic 64-VGPR/8-wave target that spilled 1.2GB of scratch.
// Live set: scores phase ~ qp[32]+spw[17]+spp[3]+64 in-flight = ~120;
// PV phase ~ acc[64]+spw+spp+32 in-flight = ~125. Both < 160.

constexpr int L       = 4096;
constexpr int E       = 64;
constexpr int QB      = 256;
constexpr int WMAX    = 32;
constexpr int WROWS   = QB + WMAX;   // 288
constexpr int RSTRIDE = 144;         // 128 B bf16 row + 16 pad
constexpr int TPB_SEQ = L / QB;      // 16
constexpr int NP2     = 6;           // dists 64..2048
constexpr int NW      = WMAX + 1;    // 33 window keys

__device__ __forceinline__ unsigned pack2_bf16(float a, float b) {
    unsigned ua = __float_as_uint(a);
    unsigned ub = __float_as_uint(b);
    unsigned ra = (ua + 0x7FFFu + ((ua >> 16) & 1u)) >> 16;  // RNE
    unsigned rb = (ub + 0x7FFFu + ((ub >> 16) & 1u)) >> 16;
    return ra | (rb << 16);
}
__device__ __forceinline__ float bf_lo(unsigned w) { return __uint_as_float(w << 16); }
__device__ __forceinline__ float bf_hi(unsigned w) { return __uint_as_float(w & 0xFFFF0000u); }

__device__ __forceinline__ unsigned pack2_f16(float a, float b) {
    unsigned lo = (unsigned)__half_as_ushort(__float2half(a));
    unsigned hi = (unsigned)__half_as_ushort(__float2half(b));
    return lo | (hi << 16);
}
__device__ __forceinline__ float up16(unsigned w, int hi) {
    unsigned short u = hi ? (unsigned short)(w >> 16) : (unsigned short)(w & 0xFFFFu);
    return __half2float(__ushort_as_half(u));
}

__global__ __launch_bounds__(256)
__attribute__((amdgpu_waves_per_eu(3, 3)))
void logsparse_attn(
    const float* __restrict__ q,
    const float* __restrict__ k,
    const float* __restrict__ v,
    float* __restrict__ out,
    const int* __restrict__ win_ptr)
{
    __shared__ alignas(16) unsigned char buf[WROWS * RSTRIDE];  // 41472 B

    const int bid = blockIdx.x, nb = gridDim.x;
    int swz = bid;
    if ((nb & 7) == 0) {                        // bijective XCD swizzle
        const int cpx = nb >> 3;
        swz = (bid & 7) * cpx + (bid >> 3);
    }
    const int bh  = swz / TPB_SEQ;
    const int t   = (swz % TPB_SEQ) * QB;
    const int tid = threadIdx.x;
    const int i   = t + tid;
    int win = *win_ptr; win = min(win, WMAX);

    const size_t base = (size_t)bh * (L * E);
    const float* kb = k + base;
    const float* vb = v + base;

    // ---- stage K window rows [t-WMAX, t+QB) as bf16 (coalesced) ----
    #pragma unroll 4
    for (int it = 0; it < (WROWS * (E / 4)) / QB; ++it) {   // 18 iters
        int idx = tid + it * QB;
        int row = idx >> 4, e4 = idx & 15;
        int j = t - WMAX + row; j = max(j, 0);
        const float4 f = *(const float4*)(kb + (size_t)j * E + e4 * 4);
        uint2 pk; pk.x = pack2_bf16(f.x, f.y); pk.y = pack2_bf16(f.z, f.w);
        *(uint2*)(buf + row * RSTRIDE + e4 * 8) = pk;
    }
    __syncthreads();

    // ---- full q row, scaled (1/8), packed bf16 -> 32 regs ----
    unsigned qp[32];
    {
        const float* qptr = q + base + (size_t)i * E;
        #pragma unroll
        for (int e4 = 0; e4 < 16; ++e4) {
            float4 f = *(const float4*)(qptr + e4 * 4);
            qp[e4*2+0] = pack2_bf16(f.x * 0.125f, f.y * 0.125f);
            qp[e4*2+1] = pack2_bf16(f.z * 0.125f, f.w * 0.125f);
        }
    }
    __builtin_amdgcn_sched_barrier(0);

    // window dot from LDS (o compile-time after unroll)
    auto win_dot = [&](int o) -> float {
        const int4* rp = (const int4*)(buf + (tid + (WMAX - o)) * RSTRIDE);
        float a0 = 0.f, a1 = 0.f, a2 = 0.f, a3 = 0.f;
        #pragma unroll
        for (int e8 = 0; e8 < 8; ++e8) {
            int4 w = rp[e8];
            unsigned q0 = qp[e8*4+0], q1 = qp[e8*4+1], q2 = qp[e8*4+2], q3 = qp[e8*4+3];
            a0 = fmaf(bf_lo(w.x), bf_lo(q0), a0); a1 = fmaf(bf_hi(w.x), bf_hi(q0), a1);
            a2 = fmaf(bf_lo(w.y), bf_lo(q1), a2); a3 = fmaf(bf_hi(w.y), bf_hi(q1), a3);
            a0 = fmaf(bf_lo(w.z), bf_lo(q2), a0); a1 = fmaf(bf_hi(w.z), bf_hi(q2), a1);
            a2 = fmaf(bf_lo(w.w), bf_lo(q3), a2); a3 = fmaf(bf_hi(w.w), bf_hi(q3), a3);
        }
        return (a0 + a1) + (a2 + a3);
    };
    auto mask_w = [&](int o, float s) -> float {
        const bool isp2  = (o > 0) && ((o & (o - 1)) == 0);
        const bool valid = ((o <= win) || isp2) && (o <= i);
        return valid ? s : -60000.f;
    };
    auto p2_dot = [&](int dd) -> float {    // dd compile-time after unroll
        const int d = 64 << dd;
        float s = -60000.f;
        if ((i | 63) >= d) {                // wave-uniform skip
            const int j = max(i - d, 0);
            const float* kr = kb + (size_t)j * E;
            float a0 = 0.f, a1 = 0.f, a2 = 0.f, a3 = 0.f;
            #pragma unroll
            for (int e4 = 0; e4 < 16; ++e4) {
                float4 f = *(const float4*)(kr + e4 * 4);
                unsigned w0 = qp[e4*2+0], w1 = qp[e4*2+1];
                a0 = fmaf(f.x, bf_lo(w0), a0); a1 = fmaf(f.y, bf_hi(w0), a1);
                a2 = fmaf(f.z, bf_lo(w1), a2); a3 = fmaf(f.w, bf_hi(w1), a3);
            }
            if (i >= d) s = (a0 + a1) + (a2 + a3);
        }
        return s;
    };

    // ---- window scores -> packed fp16 spw[17] (slot 33 = dummy) ----
    unsigned spw[17];
    #pragma unroll
    for (int op = 0; op < 17; ++op) {
        const int o0 = 2 * op, o1 = 2 * op + 1;
        float s0 = mask_w(o0, win_dot(o0));
        float s1 = (o1 < NW) ? mask_w(o1, win_dot(o1)) : -60000.f;
        spw[op] = pack2_f16(s0, s1);
        __builtin_amdgcn_sched_barrier(0);   // <=2 rows of LDS loads in flight
    }

    // ---- pow2 scores -> packed fp16 spp[3] ----
    unsigned spp[3];
    #pragma unroll
    for (int dp = 0; dp < 3; ++dp) {
        float s0 = p2_dot(2 * dp);
        __builtin_amdgcn_sched_barrier(0);   // one 64-reg load burst at a time
        float s1 = p2_dot(2 * dp + 1);
        spp[dp] = pack2_f16(s0, s1);
        __builtin_amdgcn_sched_barrier(0);
    }

    // ---- softmax folded into one constant: C = m + log(den) ----
    float m = -1e30f;
    #pragma unroll
    for (int a = 0; a < NW; ++a) m = fmaxf(m, up16(spw[a >> 1], a & 1));
    #pragma unroll
    for (int a = 0; a < NP2; ++a) m = fmaxf(m, up16(spp[a >> 1], a & 1));
    float den = 0.f;
    #pragma unroll
    for (int a = 0; a < NW; ++a) den += __expf(up16(spw[a >> 1], a & 1) - m);
    #pragma unroll
    for (int a = 0; a < NP2; ++a) den += __expf(up16(spp[a >> 1], a & 1) - m);
    const float C = m + __logf(den);

    __syncthreads();   // done reading K from buf

    // ---- restage V window rows as bf16 ----
    #pragma unroll 4
    for (int it = 0; it < (WROWS * (E / 4)) / QB; ++it) {
        int idx = tid + it * QB;
        int row = idx >> 4, e4 = idx & 15;
        int j = t - WMAX + row; j = max(j, 0);
        const float4 f = *(const float4*)(vb + (size_t)j * E + e4 * 4);
        uint2 pk; pk.x = pack2_bf16(f.x, f.y); pk.y = pack2_bf16(f.z, f.w);
        *(uint2*)(buf + row * RSTRIDE + e4 * 8) = pk;
    }
    __syncthreads();

    // ---- PV: single pass, acc[64]; p = exp(s - C) recomputed on the fly ----
    float acc[E];
    #pragma unroll
    for (int e = 0; e < E; ++e) acc[e] = 0.f;

    #pragma unroll
    for (int o = 0; o < NW; ++o) {
        const float pd = __expf(up16(spw[o >> 1], o & 1) - C);   // 0 if masked
        const int4* rp = (const int4*)(buf + (tid + (WMAX - o)) * RSTRIDE);
        #pragma unroll
        for (int e8 = 0; e8 < 8; ++e8) {
            int4 w = rp[e8]; int eb = e8 * 8;
            acc[eb+0] = fmaf(bf_lo(w.x), pd, acc[eb+0]);
            acc[eb+1] = fmaf(bf_hi(w.x), pd, acc[eb+1]);
            acc[eb+2] = fmaf(bf_lo(w.y), pd, acc[eb+2]);
            acc[eb+3] = fmaf(bf_hi(w.y), pd, acc[eb+3]);
            acc[eb+4] = fmaf(bf_lo(w.z), pd, acc[eb+4]);
            acc[eb+5] = fmaf(bf_hi(w.z), pd, acc[eb+5]);
            acc[eb+6] = fmaf(bf_lo(w.w), pd, acc[eb+6]);
            acc[eb+7] = fmaf(bf_hi(w.w), pd, acc[eb+7]);
        }
        if ((o & 1) == 1) __builtin_amdgcn_sched_barrier(0);  // <=2 rows in flight
    }

    #pragma unroll
    for (int dd = 0; dd < NP2; ++dd) {
        const int d = 64 << dd;
        const int o = NW + dd;          // index in packed layout: spp[dd>>1]
        if ((i | 63) >= d) {
            const int j = max(i - d, 0);
            const float* vr = vb + (size_t)j * E;
            const float pd = __expf(up16(spp[dd >> 1], dd & 1) - C);  // 0 if masked
            #pragma unroll
            for (int e4 = 0; e4 < 16; ++e4) {
                float4 f = *(const float4*)(vr + e4 * 4);
                acc[e4*4+0] = fmaf(f.x, pd, acc[e4*4+0]);
                acc[e4*4+1] = fmaf(f.y, pd, acc[e4*4+1]);
                acc[e4*4+2] = fmaf(f.z, pd, acc[e4*4+2]);
                acc[e4*4+3] = fmaf(f.w, pd, acc[e4*4+3]);
            }
        }
        __builtin_amdgcn_sched_barrier(0);   // one 64-reg load burst per dist
    }

    // ---- write out ----
    float* op = out + base + (size_t)i * E;
    #pragma unroll
    for (int e4 = 0; e4 < 16; ++e4) {
        float4 o4;
        o4.x = acc[e4*4+0]; o4.y = acc[e4*4+1];
        o4.z = acc[e4*4+2]; o4.w = acc[e4*4+3];
        *(float4*)(op + e4 * 4) = o4;
    }
}

extern "C" void kernel_launch(void* const* d_in, const int* in_sizes, int n_in,
                              void* d_out, int out_size, void* d_ws, size_t ws_size,
                              hipStream_t stream) {
    const float* q = (const float*)d_in[0];
    const float* k = (const float*)d_in[1];
    const float* v = (const float*)d_in[2];
    const int* win = (const int*)d_in[3];
    float* out = (float*)d_out;

    const int n_rows = in_sizes[0] / E;       // B*H*L = 131072
    const int blocks = n_rows / QB;           // 512
    logsparse_attn<<<blocks, QB, 0, stream>>>(q, k, v, out, win);
}

// Round 9
// 62.510 us; speedup vs baseline: 12.2848x; 9.8407x over previous
//
#include <hip/hip_runtime.h>

// Log-sparse attention, B=4 H=8 L=4096 E=64 fp32, win_len<=32.
// Round-9 STRUCTURAL change: QUAD-per-query (4 lanes/query, 16 elems each).
// Six rounds showed hipcc spills the lane-per-query design (needs ~150 VGPR)
// at every occupancy target. Quad design: peak live ~55 floats -> ~64 VGPR,
// 8 blocks/CU, 32 waves/CU. Cross-lane via DPP quad_perm (VALU pipe, zero
// ds_bpermute -- round 1's failure). Window K/V staged LDS bf16; scores
// distributed across the quad (lane s owns keys with key%4==s).

constexpr int L     = 4096;
constexpr int E     = 64;
constexpr int QPB   = 64;            // queries per block (256 thr / 4)
constexpr int WMAX  = 32;
constexpr int WROWS = QPB + WMAX;    // 96 staged rows
constexpr int RS    = 144;           // LDS row stride bytes (128 data + 16)
constexpr int TPB   = L / QPB;       // 64 tiles per (b,h)
constexpr int NP2   = 6;             // pow2 dists 64..2048

__device__ __forceinline__ unsigned pack2_bf16(float a, float b) {
    unsigned ua = __float_as_uint(a);
    unsigned ub = __float_as_uint(b);
    unsigned ra = (ua + 0x7FFFu + ((ua >> 16) & 1u)) >> 16;  // RNE
    unsigned rb = (ub + 0x7FFFu + ((ub >> 16) & 1u)) >> 16;
    return ra | (rb << 16);
}
__device__ __forceinline__ float bf_lo(unsigned w) { return __uint_as_float(w << 16); }
__device__ __forceinline__ float bf_hi(unsigned w) { return __uint_as_float(w & 0xFFFF0000u); }

// ---- DPP quad_perm cross-lane (VALU pipe; 4-lane groups) ----
template<int CTRL>
__device__ __forceinline__ float dppf(float x) {
    return __int_as_float(__builtin_amdgcn_update_dpp(
        0, __float_as_int(x), CTRL, 0xF, 0xF, true));
}
__device__ __forceinline__ float quad_sum(float x) {   // all 4 lanes get total
    x += dppf<0xB1>(x);   // quad_perm [1,0,3,2]
    x += dppf<0x4E>(x);   // quad_perm [2,3,0,1]
    return x;
}
__device__ __forceinline__ float quad_max(float x) {
    x = fmaxf(x, dppf<0xB1>(x));
    x = fmaxf(x, dppf<0x4E>(x));
    return x;
}
__device__ __forceinline__ float quad_bcast(float x, int r) {
    // r is compile-time after unroll; switch folds to one DPP
    switch (r & 3) {
    case 0:  return dppf<0x00>(x);
    case 1:  return dppf<0x55>(x);
    case 2:  return dppf<0xAA>(x);
    default: return dppf<0xFF>(x);
    }
}

__global__ __launch_bounds__(256) void logsparse_attn(
    const float* __restrict__ q,
    const float* __restrict__ k,
    const float* __restrict__ v,
    float* __restrict__ out,
    const int* __restrict__ win_ptr)
{
    __shared__ alignas(16) unsigned char buf[WROWS * RS];   // 13824 B

    const int bid = blockIdx.x, nb = gridDim.x;
    int swz = bid;
    if ((nb & 7) == 0) {                       // bijective XCD swizzle
        const int cpx = nb >> 3;
        swz = (bid & 7) * cpx + (bid >> 3);
    }
    const int bh  = swz / TPB;
    const int t   = (swz % TPB) * QPB;
    const int tid = threadIdx.x;
    const int qid = tid >> 2;                  // query within block (0..63)
    const int s   = tid & 3;                   // lane within quad
    const int i   = t + qid;                   // this quad's query position
    const int c   = (s + qid) & 3;             // rotated 16-elem chunk (banks)
    const int ce  = c * 16;                    // chunk base element
    int win = *win_ptr; win = min(win, WMAX);

    const size_t base = (size_t)bh * (L * E);
    const float* kb = k + base;
    const float* vb = v + base;

    // ---- stage K window rows [t-32, t+64) as bf16 (coalesced) ----
    #pragma unroll
    for (int it = 0; it < (WROWS * (E / 4)) / 256; ++it) {  // 6 iters
        int idx = tid + it * 256;
        int row = idx >> 4, e4 = idx & 15;
        int j = max(t - WMAX + row, 0);
        const float4 f = *(const float4*)(kb + (size_t)j * E + e4 * 4);
        uint2 pk; pk.x = pack2_bf16(f.x, f.y); pk.y = pack2_bf16(f.z, f.w);
        *(uint2*)(buf + row * RS + e4 * 8) = pk;
    }
    __syncthreads();

    // ---- this lane's q chunk (16 fp32), scale folded (1/8) ----
    float qv[16];
    {
        const float* qp = q + base + (size_t)i * E + ce;
        #pragma unroll
        for (int u = 0; u < 4; ++u) {
            float4 f = *(const float4*)(qp + u * 4);
            qv[u*4+0] = f.x * 0.125f; qv[u*4+1] = f.y * 0.125f;
            qv[u*4+2] = f.z * 0.125f; qv[u*4+3] = f.w * 0.125f;
        }
    }

    // ---- scores, distributed: lane s owns keys a with a%4==s ----
    float ws[9];                               // window keys o = 4k+s
    float wp[2];                               // pow2 keys
    #pragma unroll
    for (int kk = 0; kk < 9; ++kk) ws[kk] = -60000.f;
    wp[0] = wp[1] = -60000.f;

    // window offsets 0..32 from LDS (bf16; quad reads one row, 32B/lane)
    #pragma unroll
    for (int o = 0; o <= WMAX; ++o) {
        const unsigned char* rp = buf + (qid + WMAX - o) * RS + c * 32;
        int4 w0 = *(const int4*)rp;
        int4 w1 = *(const int4*)(rp + 16);
        float a0 = 0.f, a1 = 0.f, a2 = 0.f, a3 = 0.f;
        a0 = fmaf(bf_lo(w0.x), qv[0],  a0); a1 = fmaf(bf_hi(w0.x), qv[1],  a1);
        a2 = fmaf(bf_lo(w0.y), qv[2],  a2); a3 = fmaf(bf_hi(w0.y), qv[3],  a3);
        a0 = fmaf(bf_lo(w0.z), qv[4],  a0); a1 = fmaf(bf_hi(w0.z), qv[5],  a1);
        a2 = fmaf(bf_lo(w0.w), qv[6],  a2); a3 = fmaf(bf_hi(w0.w), qv[7],  a3);
        a0 = fmaf(bf_lo(w1.x), qv[8],  a0); a1 = fmaf(bf_hi(w1.x), qv[9],  a1);
        a2 = fmaf(bf_lo(w1.y), qv[10], a2); a3 = fmaf(bf_hi(w1.y), qv[11], a3);
        a0 = fmaf(bf_lo(w1.z), qv[12], a0); a1 = fmaf(bf_hi(w1.z), qv[13], a1);
        a2 = fmaf(bf_lo(w1.w), qv[14], a2); a3 = fmaf(bf_hi(w1.w), qv[15], a3);
        float sv = quad_sum((a0 + a1) + (a2 + a3));
        const bool isp2  = (o > 0) && ((o & (o - 1)) == 0);
        const bool valid = ((o <= win) || isp2) && (o <= i);
        sv = valid ? sv : -60000.f;
        if (s == (o & 3)) ws[o >> 2] = sv;     // owner keeps
        if ((o & 1) == 1) __builtin_amdgcn_sched_barrier(0);
    }

    // pow2 dists 64..2048 (global fp32; quad reads one 256B row)
    #pragma unroll
    for (int dd = 0; dd < NP2; ++dd) {
        const int d = 64 << dd;
        if (t + QPB - 1 >= d) {                // block-uniform skip
            const int j = max(i - d, 0);
            const float* kr = kb + (size_t)j * E + ce;
            float a0 = 0.f, a1 = 0.f, a2 = 0.f, a3 = 0.f;
            #pragma unroll
            for (int u = 0; u < 4; ++u) {
                float4 f = *(const float4*)(kr + u * 4);
                a0 = fmaf(f.x, qv[u*4+0], a0); a1 = fmaf(f.y, qv[u*4+1], a1);
                a2 = fmaf(f.z, qv[u*4+2], a2); a3 = fmaf(f.w, qv[u*4+3], a3);
            }
            float sv = quad_sum((a0 + a1) + (a2 + a3));
            sv = (i >= d) ? sv : -60000.f;
            if (s == ((WMAX + 1 + dd) & 3)) wp[dd < 4 ? 0 : 1] = sv;
        }
        __builtin_amdgcn_sched_barrier(0);
    }

    // ---- softmax across the quad's distributed scores ----
    float ml = ws[0];
    #pragma unroll
    for (int kk = 1; kk < 9; ++kk) ml = fmaxf(ml, ws[kk]);
    ml = fmaxf(ml, fmaxf(wp[0], wp[1]));
    const float m = quad_max(ml);

    float ew[9], ep0, ep1, dl = 0.f;
    #pragma unroll
    for (int kk = 0; kk < 9; ++kk) { ew[kk] = __expf(ws[kk] - m); dl += ew[kk]; }
    ep0 = __expf(wp[0] - m); ep1 = __expf(wp[1] - m); dl += ep0 + ep1;
    const float inv = 1.0f / quad_sum(dl);
    #pragma unroll
    for (int kk = 0; kk < 9; ++kk) ew[kk] *= inv;
    ep0 *= inv; ep1 *= inv;

    __syncthreads();   // done reading K from buf

    // ---- restage V window rows as bf16 ----
    #pragma unroll
    for (int it = 0; it < (WROWS * (E / 4)) / 256; ++it) {
        int idx = tid + it * 256;
        int row = idx >> 4, e4 = idx & 15;
        int j = max(t - WMAX + row, 0);
        const float4 f = *(const float4*)(vb + (size_t)j * E + e4 * 4);
        uint2 pk; pk.x = pack2_bf16(f.x, f.y); pk.y = pack2_bf16(f.z, f.w);
        *(uint2*)(buf + row * RS + e4 * 8) = pk;
    }
    __syncthreads();

    // ---- PV: acc[16] per lane ----
    float acc[16];
    #pragma unroll
    for (int e = 0; e < 16; ++e) acc[e] = 0.f;

    #pragma unroll
    for (int o = 0; o <= WMAX; ++o) {
        const float pd = quad_bcast(ew[o >> 2], o & 3);   // owner's weight
        const unsigned char* rp = buf + (qid + WMAX - o) * RS + c * 32;
        int4 w0 = *(const int4*)rp;
        int4 w1 = *(const int4*)(rp + 16);
        acc[0]  = fmaf(bf_lo(w0.x), pd, acc[0]);  acc[1]  = fmaf(bf_hi(w0.x), pd, acc[1]);
        acc[2]  = fmaf(bf_lo(w0.y), pd, acc[2]);  acc[3]  = fmaf(bf_hi(w0.y), pd, acc[3]);
        acc[4]  = fmaf(bf_lo(w0.z), pd, acc[4]);  acc[5]  = fmaf(bf_hi(w0.z), pd, acc[5]);
        acc[6]  = fmaf(bf_lo(w0.w), pd, acc[6]);  acc[7]  = fmaf(bf_hi(w0.w), pd, acc[7]);
        acc[8]  = fmaf(bf_lo(w1.x), pd, acc[8]);  acc[9]  = fmaf(bf_hi(w1.x), pd, acc[9]);
        acc[10] = fmaf(bf_lo(w1.y), pd, acc[10]); acc[11] = fmaf(bf_hi(w1.y), pd, acc[11]);
        acc[12] = fmaf(bf_lo(w1.z), pd, acc[12]); acc[13] = fmaf(bf_hi(w1.z), pd, acc[13]);
        acc[14] = fmaf(bf_lo(w1.w), pd, acc[14]); acc[15] = fmaf(bf_hi(w1.w), pd, acc[15]);
        if ((o & 1) == 1) __builtin_amdgcn_sched_barrier(0);
    }

    #pragma unroll
    for (int dd = 0; dd < NP2; ++dd) {
        const int d = 64 << dd;
        if (t + QPB - 1 >= d) {                // block-uniform skip
            const float pd = quad_bcast(dd < 4 ? ep0 : ep1, (WMAX + 1 + dd) & 3);
            const int j = max(i - d, 0);
            const float* vr = vb + (size_t)j * E + ce;
            #pragma unroll
            for (int u = 0; u < 4; ++u) {
                float4 f = *(const float4*)(vr + u * 4);
                acc[u*4+0] = fmaf(f.x, pd, acc[u*4+0]);
                acc[u*4+1] = fmaf(f.y, pd, acc[u*4+1]);
                acc[u*4+2] = fmaf(f.z, pd, acc[u*4+2]);
                acc[u*4+3] = fmaf(f.w, pd, acc[u*4+3]);
            }
        }
        __builtin_amdgcn_sched_barrier(0);
    }

    // ---- write this lane's 64B chunk ----
    float* op = out + base + (size_t)i * E + ce;
    #pragma unroll
    for (int u = 0; u < 4; ++u) {
        float4 o4;
        o4.x = acc[u*4+0]; o4.y = acc[u*4+1];
        o4.z = acc[u*4+2]; o4.w = acc[u*4+3];
        *(float4*)(op + u * 4) = o4;
    }
}

extern "C" void kernel_launch(void* const* d_in, const int* in_sizes, int n_in,
                              void* d_out, int out_size, void* d_ws, size_t ws_size,
                              hipStream_t stream) {
    const float* q = (const float*)d_in[0];
    const float* k = (const float*)d_in[1];
    const float* v = (const float*)d_in[2];
    const int* win = (const int*)d_in[3];
    float* out = (float*)d_out;

    const int n_rows = in_sizes[0] / E;        // B*H*L = 131072
    const int blocks = n_rows / QPB;           // 2048
    logsparse_attn<<<blocks, 256, 0, stream>>>(q, k, v, out, win);
}